// Round 7
// baseline (562.673 us; speedup 1.0000x reference)
//
#include <hip/hip_runtime.h>

// Problem constants (from reference file)
#define N0_SRC 200000
#define N1_DST 50000
#define N2_DST 12000
#define N3_DST 3000
#define NTOT_DST 65000   // N1+N2+N3 (multiple of 4; scan uses 64 blocks)
#define DH 256           // D_IN == D_H == 256
#define DOUT 64
#define EMAX_TOT 650000  // E0+E1+E2

typedef __attribute__((ext_vector_type(8))) short short8;
typedef __attribute__((ext_vector_type(4))) float f32x4;

__device__ __forceinline__ ushort f2bf(float f) {
    union { float f; uint32_t u; } v; v.f = f;
    uint32_t r = (v.u + 0x7FFF + ((v.u >> 16) & 1)) >> 16;  // RNE
    return (ushort)r;
}
__device__ __forceinline__ float bf2f(ushort u) {
    union { uint32_t u; float f; } v; v.u = ((uint32_t)u) << 16;
    return v.f;
}

// ---------------------------------------------------------------------------
// Mega-kernel: fuses three INDEPENDENT jobs so the BW-bound convert overlaps
// the atomic-latency-bound histogram (m114: different pipes co-schedule).
//   blocks [0, CB)              : x fp32 -> bf16 convert (CB = N0*DH/1024)
//   blocks [CB, CB+1536)        : 6 weight transposes (256 blocks each)
//   blocks [CB+1536, ...)       : hist for layers 0,1,2 (dst histogram)
// ---------------------------------------------------------------------------
#define CONV_BLOCKS (N0_SRC * DH / 1024)  // 50000
#define TRANS_BLOCKS 1536

__global__ void mega_prep_kernel(const float* __restrict__ x, ushort* __restrict__ xb,
                                 const float* __restrict__ W0, const float* __restrict__ W1,
                                 const float* __restrict__ W2, const float* __restrict__ W3,
                                 const float* __restrict__ W4, const float* __restrict__ W5,
                                 ushort* __restrict__ Wt,
                                 const int* __restrict__ d0, int E0,
                                 const int* __restrict__ d1, int E1,
                                 const int* __restrict__ d2, int E2,
                                 int hb0, int hb1,  // hist block counts for layers 0,1
                                 int* __restrict__ cnt) {
    int bid = blockIdx.x;
    int tid = threadIdx.x;
    if (bid < CONV_BLOCKS) {
        long i = ((long)bid * 256 + tid) * 4;
        float4 v = *(const float4*)(x + i);
        ushort4 o;
        o.x = f2bf(v.x); o.y = f2bf(v.y); o.z = f2bf(v.z); o.w = f2bf(v.w);
        *(ushort4*)(xb + i) = o;
        return;
    }
    bid -= CONV_BLOCKS;
    if (bid < TRANS_BLOCKS) {
        int wsel = bid >> 8;        // 0..5
        int blk  = bid & 255;
        const float* W; int Ndim; ushort* o;
        switch (wsel) {
            case 0: W = W0; Ndim = 256; o = Wt; break;
            case 1: W = W1; Ndim = 256; o = Wt + 65536; break;
            case 2: W = W2; Ndim = 256; o = Wt + 131072; break;
            case 3: W = W3; Ndim = 256; o = Wt + 196608; break;
            case 4: W = W4; Ndim = 64;  o = Wt + 262144; break;
            default: W = W5; Ndim = 64; o = Wt + 278528; break;
        }
        int id = blk * 256 + tid;   // id = n*256 + k
        int n = id >> 8;
        int k = id & 255;
        if (n < Ndim) o[id] = f2bf(W[k * Ndim + n]);
        return;
    }
    bid -= TRANS_BLOCKS;
    const int* dst; int E; int base;
    if (bid < hb0)            { dst = d0; E = E0; base = 0; }
    else if (bid < hb0 + hb1) { dst = d1; E = E1; base = N1_DST; bid -= hb0; }
    else                      { dst = d2; E = E2; base = N1_DST + N2_DST; bid -= hb0 + hb1; }
    int e = bid * 256 + tid;
    if (e < E) atomicAdd(&cnt[base + dst[e]], 1);
}

// ---------------------------------------------------------------------------
// 3-phase coalesced exclusive scan (n multiple of 4; n <= 64*1024)
// ---------------------------------------------------------------------------
__global__ void scan_phase_a(const int* __restrict__ cnt, int* __restrict__ partial, int n) {
    __shared__ int red[4];
    int t = threadIdx.x;
    int i = blockIdx.x * 1024 + t * 4;
    int s = 0;
    if (i + 3 < n) {
        int4 v = *(const int4*)(cnt + i);
        s = v.x + v.y + v.z + v.w;
    }
#pragma unroll
    for (int d = 32; d; d >>= 1) s += __shfl_down(s, d, 64);
    if ((t & 63) == 0) red[t >> 6] = s;
    __syncthreads();
    if (t == 0) partial[blockIdx.x] = red[0] + red[1] + red[2] + red[3];
}

__global__ void scan_phase_b(int* __restrict__ partial, int nb) {
    int t = threadIdx.x;  // 64 threads
    int own = (t < nb) ? partial[t] : 0;
    int v = own;
#pragma unroll
    for (int d = 1; d < 64; d <<= 1) {
        int u = __shfl_up(v, d, 64);
        if (t >= d) v += u;
    }
    if (t < nb) partial[t] = v - own;  // exclusive
}

__global__ void scan_phase_c(const int* __restrict__ cnt, const int* __restrict__ partial,
                             int* __restrict__ off, int* __restrict__ cursor, int n) {
    __shared__ int tsum[256];
    int t = threadIdx.x;
    int i = blockIdx.x * 1024 + t * 4;
    int4 c = make_int4(0, 0, 0, 0);
    if (i + 3 < n) c = *(const int4*)(cnt + i);
    int s = c.x + c.y + c.z + c.w;
    tsum[t] = s;
    __syncthreads();
#pragma unroll
    for (int d = 1; d < 256; d <<= 1) {
        int u = (t >= d) ? tsum[t - d] : 0;
        __syncthreads();
        tsum[t] += u;
        __syncthreads();
    }
    int base = partial[blockIdx.x] + tsum[t] - s;
    if (i + 3 < n) {
        int4 ov;
        ov.x = base;
        ov.y = ov.x + c.x;
        ov.z = ov.y + c.y;
        ov.w = ov.z + c.z;
        *(int4*)(off + i) = ov;
        *(int4*)(cursor + i) = ov;
        if (i + 4 == n) off[n] = ov.w + c.w;
    }
}

// ---------------------------------------------------------------------------
// CSR fill, all 3 layers in one launch
// ---------------------------------------------------------------------------
__global__ void fill3_kernel(const int* __restrict__ s0, const int* __restrict__ d0, int E0,
                             const int* __restrict__ s1, const int* __restrict__ d1, int E1,
                             const int* __restrict__ s2, const int* __restrict__ d2, int E2,
                             int* __restrict__ cursor, int* __restrict__ eidx) {
    int layer = blockIdx.y;
    const int* src; const int* dst; int E; int base;
    if (layer == 0)      { src = s0; dst = d0; E = E0; base = 0; }
    else if (layer == 1) { src = s1; dst = d1; E = E1; base = N1_DST; }
    else                 { src = s2; dst = d2; E = E2; base = N1_DST + N2_DST; }
    int e = blockIdx.x * 256 + threadIdx.x;
    if (e < E) {
        int p = atomicAdd(&cursor[base + dst[e]], 1);
        eidx[p] = src[e];
    }
}

// ---------------------------------------------------------------------------
// Gather-mean, bf16 in -> bf16 out. One wave per dst; lane owns 4 feats.
// ---------------------------------------------------------------------------
__global__ void gather_mean_bf16_kernel(const ushort* __restrict__ h,
                                        const int* __restrict__ off,
                                        const int* __restrict__ eidx,
                                        ushort* __restrict__ hn,
                                        int num_dst) {
    int w = blockIdx.x * 4 + (threadIdx.x >> 6);
    int lane = threadIdx.x & 63;
    if (w >= num_dst) return;
    int beg = off[w];
    int end = off[w + 1];
    float a0 = 0.f, a1 = 0.f, a2 = 0.f, a3 = 0.f;
    int i = beg;
    for (; i + 3 < end; i += 4) {
        int s0 = eidx[i], s1 = eidx[i + 1], s2 = eidx[i + 2], s3 = eidx[i + 3];
        ushort4 v0 = ((const ushort4*)(h + (size_t)s0 * DH))[lane];
        ushort4 v1 = ((const ushort4*)(h + (size_t)s1 * DH))[lane];
        ushort4 v2 = ((const ushort4*)(h + (size_t)s2 * DH))[lane];
        ushort4 v3 = ((const ushort4*)(h + (size_t)s3 * DH))[lane];
        a0 += (bf2f(v0.x) + bf2f(v1.x)) + (bf2f(v2.x) + bf2f(v3.x));
        a1 += (bf2f(v0.y) + bf2f(v1.y)) + (bf2f(v2.y) + bf2f(v3.y));
        a2 += (bf2f(v0.z) + bf2f(v1.z)) + (bf2f(v2.z) + bf2f(v3.z));
        a3 += (bf2f(v0.w) + bf2f(v1.w)) + (bf2f(v2.w) + bf2f(v3.w));
    }
    for (; i < end; ++i) {
        int s0 = eidx[i];
        ushort4 v0 = ((const ushort4*)(h + (size_t)s0 * DH))[lane];
        a0 += bf2f(v0.x); a1 += bf2f(v0.y); a2 += bf2f(v0.z); a3 += bf2f(v0.w);
    }
    float inv = 1.0f / fmaxf((float)(end - beg), 1.0f);
    ushort4 o;
    o.x = f2bf(a0 * inv); o.y = f2bf(a1 * inv);
    o.z = f2bf(a2 * inv); o.w = f2bf(a3 * inv);
    *(ushort4*)(hn + (size_t)w * DH + lane * 4) = o;
}

// ---------------------------------------------------------------------------
// MFMA dual GEMM: C[M,N] = Ad@Ws + An@Wn + bias (K=256). A: M x K bf16
// row-major. Wt: N x K bf16 (pre-transposed).
// Block: 128 x BN tile, 4 waves. BK=64 (8 k-steps total over both passes).
//  BN=128: waves 2x2, each 64x64 (MT=4,NT=4)
//  BN=64 : waves 4x1, each 32x64 (MT=2,NT=4)
// ---------------------------------------------------------------------------
template <int BN, bool RELU, bool OUT_BF16>
__global__ void gemm_mfma(const ushort* __restrict__ Ad,
                          const ushort* __restrict__ An,
                          const ushort* __restrict__ Wst,
                          const ushort* __restrict__ Wnt,
                          const float* __restrict__ bias,
                          void* __restrict__ Cv,
                          int M, int N) {
    const int K = 256;
    const int BK = 64;
    const int LDK = 72;  // padded k-stride (shorts): 144B rows
    const int MT = (BN == 128) ? 4 : 2;
    const int NT = 4;
    __shared__ ushort As[128 * LDK];
    __shared__ ushort Bs[BN * LDK];

    int tid  = threadIdx.x;
    int lane = tid & 63;
    int wid  = tid >> 6;
    int quad = lane >> 4;
    int mr   = lane & 15;
    int row0 = blockIdx.y * 128;
    int col0 = blockIdx.x * BN;
    int wm   = (BN == 128) ? (wid >> 1) * 64 : wid * 32;
    int wn   = (BN == 128) ? (wid & 1) * 64 : 0;

    f32x4 acc[MT][NT];
#pragma unroll
    for (int i = 0; i < MT; ++i)
#pragma unroll
        for (int j = 0; j < NT; ++j) acc[i][j] = (f32x4){0.f, 0.f, 0.f, 0.f};

    for (int pass = 0; pass < 2; ++pass) {
        const ushort* A  = pass ? An : Ad;
        const ushort* Wt = pass ? Wnt : Wst;
        for (int k0 = 0; k0 < K; k0 += BK) {
            // Stage A tile: 128 rows x 64 k = 1024 16B-chunks; 4/thread
#pragma unroll
            for (int c = 0; c < 4; ++c) {
                int chunk = tid + c * 256;
                int r   = chunk >> 3;
                int seg = chunk & 7;
                int row = row0 + r;
                uint4 v = make_uint4(0u, 0u, 0u, 0u);
                if (row < M) v = *(const uint4*)(A + (size_t)row * K + k0 + seg * 8);
                *(uint4*)(&As[r * LDK + seg * 8]) = v;
            }
            // Stage B tile: BN n-rows x 64 k; BN/32 chunks per thread
#pragma unroll
            for (int c = 0; c < BN / 32; ++c) {
                int chunk = tid + c * 256;
                int n   = chunk >> 3;
                int seg = chunk & 7;
                uint4 v = *(const uint4*)(Wt + (size_t)(col0 + n) * K + k0 + seg * 8);
                *(uint4*)(&Bs[n * LDK + seg * 8]) = v;
            }
            __syncthreads();
#pragma unroll
            for (int ks = 0; ks < BK; ks += 32) {
                short8 a[MT], b[NT];
#pragma unroll
                for (int mt = 0; mt < MT; ++mt)
                    a[mt] = *(const short8*)(&As[(wm + mt * 16 + mr) * LDK + ks + quad * 8]);
#pragma unroll
                for (int nt = 0; nt < NT; ++nt)
                    b[nt] = *(const short8*)(&Bs[(wn + nt * 16 + mr) * LDK + ks + quad * 8]);
#pragma unroll
                for (int mt = 0; mt < MT; ++mt)
#pragma unroll
                    for (int nt = 0; nt < NT; ++nt)
                        acc[mt][nt] = __builtin_amdgcn_mfma_f32_16x16x32_bf16(
                            a[mt], b[nt], acc[mt][nt], 0, 0, 0);
            }
            __syncthreads();
        }
    }

    // Epilogue: C/D layout col = lane&15, row = quad*4 + reg
#pragma unroll
    for (int mt = 0; mt < MT; ++mt) {
#pragma unroll
        for (int i = 0; i < 4; ++i) {
            int row = row0 + wm + mt * 16 + quad * 4 + i;
            if (row >= M) continue;
#pragma unroll
            for (int nt = 0; nt < NT; ++nt) {
                int col = col0 + wn + nt * 16 + mr;
                float v = acc[mt][nt][i] + bias[col];
                if (RELU) v = fmaxf(v, 0.0f);
                if (OUT_BF16) ((ushort*)Cv)[(size_t)row * N + col] = f2bf(v);
                else          ((float*)Cv)[(size_t)row * N + col] = v;
            }
        }
    }
}

extern "C" void kernel_launch(void* const* d_in, const int* in_sizes, int n_in,
                              void* d_out, int out_size, void* d_ws, size_t ws_size,
                              hipStream_t stream) {
    const float* x    = (const float*)d_in[0];
    const int* src0   = (const int*)d_in[1];
    const int* dst0   = (const int*)d_in[2];
    const int* src1   = (const int*)d_in[3];
    const int* dst1   = (const int*)d_in[4];
    const int* src2   = (const int*)d_in[5];
    const int* dst2   = (const int*)d_in[6];
    const float* Ws0  = (const float*)d_in[10];
    const float* Wn0  = (const float*)d_in[11];
    const float* b0   = (const float*)d_in[12];
    const float* Ws1  = (const float*)d_in[13];
    const float* Wn1  = (const float*)d_in[14];
    const float* b1   = (const float*)d_in[15];
    const float* Ws2  = (const float*)d_in[16];
    const float* Wn2  = (const float*)d_in[17];
    const float* b2   = (const float*)d_in[18];
    float* out = (float*)d_out;

    int E0 = in_sizes[1];
    int E1 = in_sizes[3];
    int E2 = in_sizes[5];

    // Workspace layout (shorts first, then ints; all 16B aligned)
    ushort* wsu  = (ushort*)d_ws;
    ushort* xb   = wsu;                               // N0*256 (all of x, bf16)
    ushort* hn0b = xb   + (size_t)N0_SRC * DH;        // N1*256
    ushort* h1b  = hn0b + (size_t)N1_DST * DH;        // N1*256
    ushort* hn1b = h1b  + (size_t)N1_DST * DH;        // N2*256
    ushort* h2b  = hn1b + (size_t)N2_DST * DH;        // N2*256
    ushort* hn2b = h2b  + (size_t)N2_DST * DH;        // N3*256
    ushort* Wt   = hn2b + (size_t)N3_DST * DH;        // 294912 shorts (6 weights)
    ushort* Ws0t = Wt;
    ushort* Wn0t = Wt + 65536;
    ushort* Ws1t = Wt + 131072;
    ushort* Wn1t = Wt + 196608;
    ushort* Ws2t = Wt + 262144;
    ushort* Wn2t = Wt + 278528;
    int* cnt     = (int*)(Wt + 294912);               // NTOT_DST
    int* off     = cnt + NTOT_DST;                    // NTOT_DST+1 (+pad)
    int* cursor  = off + NTOT_DST + 4;                // NTOT_DST
    int* eidx    = cursor + NTOT_DST;                 // EMAX_TOT
    int* partial = eidx + EMAX_TOT;                   // 64 block partials

    // --- Fused prep: x->bf16 convert || weight transposes || dst histograms ---
    int hb0 = (E0 + 255) / 256;
    int hb1 = (E1 + 255) / 256;
    int hb2 = (E2 + 255) / 256;
    hipMemsetAsync(cnt, 0, NTOT_DST * sizeof(int), stream);
    int mega_blocks = CONV_BLOCKS + TRANS_BLOCKS + hb0 + hb1 + hb2;
    mega_prep_kernel<<<mega_blocks, 256, 0, stream>>>(
        x, xb, Ws0, Wn0, Ws1, Wn1, Ws2, Wn2, Wt,
        dst0, E0, dst1, E1, dst2, E2, hb0, hb1, cnt);

    // --- Scan + fill (batched CSR over all 3 layers) ---
    int nb = (NTOT_DST + 1023) / 1024;  // = 64
    scan_phase_a<<<nb, 256, 0, stream>>>(cnt, partial, NTOT_DST);
    scan_phase_b<<<1, 64, 0, stream>>>(partial, nb);
    scan_phase_c<<<nb, 256, 0, stream>>>(cnt, partial, off, cursor, NTOT_DST);
    int Emax = max(max(E0, E1), E2);
    fill3_kernel<<<dim3((Emax + 255) / 256, 3), 256, 0, stream>>>(
        src0, dst0, E0, src1, dst1, E1, src2, dst2, E2, cursor, eidx);

    const int* off0 = off;
    const int* off1 = off + N1_DST;
    const int* off2 = off + N1_DST + N2_DST;

    // ---- Layer 0: x -> h1 ----
    gather_mean_bf16_kernel<<<(N1_DST + 3) / 4, 256, 0, stream>>>(xb, off0, eidx, hn0b, N1_DST);
    {
        dim3 g(DH / 128, (N1_DST + 127) / 128);
        gemm_mfma<128, false, true><<<g, 256, 0, stream>>>(xb, hn0b, Ws0t, Wn0t, b0, h1b, N1_DST, DH);
    }

    // ---- Layer 1: h1 -> h2 (ReLU on output) ----
    gather_mean_bf16_kernel<<<(N2_DST + 3) / 4, 256, 0, stream>>>(h1b, off1, eidx, hn1b, N2_DST);
    {
        dim3 g(DH / 128, (N2_DST + 127) / 128);
        gemm_mfma<128, true, true><<<g, 256, 0, stream>>>(h1b, hn1b, Ws1t, Wn1t, b1, h2b, N2_DST, DH);
    }

    // ---- Layer 2: h2 -> out (fp32 output) ----
    gather_mean_bf16_kernel<<<(N3_DST + 3) / 4, 256, 0, stream>>>(h2b, off2, eidx, hn2b, N3_DST);
    {
        dim3 g(DOUT / 64, (N3_DST + 127) / 128);
        gemm_mfma<64, false, false><<<g, 256, 0, stream>>>(h2b, hn2b, Ws2t, Wn2t, b2, out, N3_DST, DOUT);
    }
}